// Round 9
// baseline (15.742 us; speedup 1.0000x reference)
//
#include <hip/hip_runtime.h>
#include <math.h>

// HybridSymmetricLoss: B=8192, P=4, M=12, 24 perms.
// pairS[p][q] = sum_{i,j} (y[p] ? log a[q] : log1p(-a[q]))  (negated BCE)
// best perm = argmax_sigma sum_p pairS[p][sigma(p)]; category BCE via sigma.
// kernel1: 1 batch per 64-lane wave, 4 waves/block, 2048 blocks.
//   Category BCE precomputed wave-parallel (catv per (p,q) group) and folded
//   into the perm gather/max-butterfly -- no lane-0 serial log chain.
//   Per-WAVE result stored directly (no LDS, no __syncthreads).
// kernel2: single-block reduce of 8192 partials, fixed order, fp64.

#define LOG2_CLIP (-144.26950408889634f)   // -100 / ln(2)
#define LN2F      (0.6931471805599453f)

// perm table, lexicographic. byte p = 16*p + 4*sigma(p) = gather lane
// (also the lane holding catv[4p+sigma(p)]); sigma(p) = (byte_p >> 2) & 3.
#define PK(a,b,c,d) ((unsigned)((4u*(a)) | ((16u+4u*(b))<<8) | \
                                ((32u+4u*(c))<<16) | ((48u+4u*(d))<<24)))
__device__ const unsigned PERM_PK[32] = {
    PK(0,1,2,3), PK(0,1,3,2), PK(0,2,1,3), PK(0,2,3,1), PK(0,3,1,2), PK(0,3,2,1),
    PK(1,0,2,3), PK(1,0,3,2), PK(1,2,0,3), PK(1,2,3,0), PK(1,3,0,2), PK(1,3,2,0),
    PK(2,0,1,3), PK(2,0,3,1), PK(2,1,0,3), PK(2,1,3,0), PK(2,3,0,1), PK(2,3,1,0),
    PK(3,0,1,2), PK(3,0,2,1), PK(3,1,0,2), PK(3,1,2,0), PK(3,2,0,1), PK(3,2,1,0),
    PK(0,1,2,3), PK(0,1,2,3), PK(0,1,2,3), PK(0,1,2,3),
    PK(0,1,2,3), PK(0,1,2,3), PK(0,1,2,3), PK(0,1,2,3)
};

__global__ __launch_bounds__(256) void hsl_partial(
    const float* __restrict__ assign,    // [B,4,12,12]
    const float* __restrict__ cat,       // [B,4]
    const float* __restrict__ alabels,   // [B,4,12,12]
    const float* __restrict__ clabels,   // [B,4]
    float* __restrict__ bsums)           // [4*nblocks] per-wave partial
{
    const int tid  = (int)threadIdx.x;
    const int wib  = tid >> 6;               // wave in block, 0..3
    const int lane = tid & 63;
    const int b    = (int)blockIdx.x * 4 + wib;

    const float* __restrict__ A = assign  + (size_t)b * 576;
    const float* __restrict__ Y = alabels + (size_t)b * 576;

    // ---- wave-parallel category BCE table: lane group g = lane>>2 maps to
    // (p = g>>2, q = g&3); all 4 lanes of a group compute the same value,
    // so catv[4p+q] lives (in particular) on lane 4*(4p+q) -- the same lane
    // the PK gather bytes address. Independent of the main loop.
    float catv;
    {
        const int gq = (lane >> 2) & 3;
        const int gp = (lane >> 4) & 3;
        const float cq  = cat[(size_t)b * 4 + gq];
        const float cyp = clabels[(size_t)b * 4 + gp];
        catv = (cyp != 0.0f) ? fmaxf(__log2f(cq), LOG2_CLIP)
                             : fmaxf(__log2f(1.0f - cq), LOG2_CLIP);
    }

    // s[4p+q] += y[p]*(la[q]-lb[q]);  T[q] += lb[q]   (log2 domain)
    float s[16], T[4];
#pragma unroll
    for (int i = 0; i < 16; ++i) s[i] = 0.0f;
#pragma unroll
    for (int i = 0; i < 4; ++i) T[i] = 0.0f;

#pragma unroll
    for (int it = 0; it < 3; ++it) {
        if (it < 2 || lane < 16) {           // e = lane + 64*it < 144
            const int e = lane + it * 64;
            float d[4], y[4];
#pragma unroll
            for (int q = 0; q < 4; ++q) {
                const float a  = A[q * 144 + e];
                const float la = fmaxf(__log2f(a),        LOG2_CLIP);
                const float lb = fmaxf(__log2f(1.0f - a), LOG2_CLIP);
                d[q] = la - lb;
                T[q] += lb;
            }
#pragma unroll
            for (int p = 0; p < 4; ++p) y[p] = Y[p * 144 + e];
#pragma unroll
            for (int p = 0; p < 4; ++p)
#pragma unroll
                for (int q = 0; q < 4; ++q)
                    s[p * 4 + q] = fmaf(y[p], d[q], s[p * 4 + q]);
        }
    }
#pragma unroll
    for (int i = 0; i < 16; ++i) s[i] += T[i & 3];

    // reduce-scatter butterfly: after 4 split stages lane l holds partial of
    // s[l>>2]; 2 more stages complete the 64-lane sum.
    const bool h32 = (lane & 32) != 0;
    const bool h16 = (lane & 16) != 0;
    const bool h8  = (lane & 8)  != 0;
    const bool h4  = (lane & 4)  != 0;

    float t[8];
#pragma unroll
    for (int i = 0; i < 8; ++i) {
        const float keep = h32 ? s[i + 8] : s[i];
        const float send = h32 ? s[i]     : s[i + 8];
        t[i] = keep + __shfl_xor(send, 32, 64);
    }
    float u[4];
#pragma unroll
    for (int i = 0; i < 4; ++i) {
        const float keep = h16 ? t[i + 4] : t[i];
        const float send = h16 ? t[i]     : t[i + 4];
        u[i] = keep + __shfl_xor(send, 16, 64);
    }
    float w[2];
#pragma unroll
    for (int i = 0; i < 2; ++i) {
        const float keep = h8 ? u[i + 2] : u[i];
        const float send = h8 ? u[i]     : u[i + 2];
        w[i] = keep + __shfl_xor(send, 8, 64);
    }
    float x;
    {
        const float keep = h4 ? w[1] : w[0];
        const float send = h4 ? w[0] : w[1];
        x = keep + __shfl_xor(send, 4, 64);
    }
    x += __shfl_xor(x, 2, 64);
    x += __shfl_xor(x, 1, 64);
    // lane l: x == total s[l >> 2]

    // perm-parallel scoring: lane j < 24 evaluates perm j; gather BOTH the
    // assignment totals (x) and the category table (catv) with the same
    // addresses, and carry the category sum through the max-butterfly.
    unsigned pk = PERM_PK[lane & 31];
    const int a0 = (int)( pk        & 0xFFu);
    const int a1 = (int)((pk >> 8)  & 0xFFu);
    const int a2 = (int)((pk >> 16) & 0xFFu);
    const int a3 = (int)( pk >> 24        );
    const float v0 = __shfl(x, a0, 64);
    const float v1 = __shfl(x, a1, 64);
    const float v2 = __shfl(x, a2, 64);
    const float v3 = __shfl(x, a3, 64);
    const float c0 = __shfl(catv, a0, 64);
    const float c1 = __shfl(catv, a1, 64);
    const float c2 = __shfl(catv, a2, 64);
    const float c3 = __shfl(catv, a3, 64);
    float score = (v0 + v1) + (v2 + v3);
    float csum  = (c0 + c1) + (c2 + c3);
    if (lane >= 24) score = -__builtin_huge_valf();

    // max-butterfly over lanes 0..31 (covers all 24 perms), carry csum
#pragma unroll
    for (int m = 16; m >= 1; m >>= 1) {
        const float os = __shfl_xor(score, m, 64);
        const float oc = __shfl_xor(csum,  m, 64);
        const bool take = os > score;
        score = take ? os : score;
        csum  = take ? oc : csum;
    }

    if (lane == 0) {
        // per-batch contribution (>= 0): -ln2 * (score/576 + csum/8)
        bsums[(size_t)blockIdx.x * 4 + wib] =
            -LN2F * (score * (1.0f / 576.0f) + 0.125f * csum);
    }
}

__global__ __launch_bounds__(256) void hsl_reduce(
    const float* __restrict__ bsums,     // [n] per-wave partials
    float* __restrict__ out,
    int n, int B)
{
    __shared__ double sw[4];
    const int tid  = (int)threadIdx.x;
    const int wid  = tid >> 6;
    const int lane = tid & 63;

    // n = 8192 -> 2048 float4; 256 threads -> 8 each, fixed assignment
    const float4* __restrict__ v4 = (const float4*)bsums;
    const int n4 = n >> 2;
    double d = 0.0;
    for (int i = tid; i < n4; i += 256) {
        const float4 v = v4[i];
        d += (double)((v.x + v.y) + (v.z + v.w));
    }

    // per-wave butterfly, no barriers, fixed order
#pragma unroll
    for (int m = 32; m >= 1; m >>= 1)
        d += __shfl_xor(d, m, 64);

    if (lane == 0) sw[wid] = d;
    __syncthreads();

    if (tid == 0) {
        const double t = (sw[0] + sw[1]) + (sw[2] + sw[3]);
        out[0] = (float)(t / (double)B);
    }
}

extern "C" void kernel_launch(void* const* d_in, const int* in_sizes, int n_in,
                              void* d_out, int out_size, void* d_ws, size_t ws_size,
                              hipStream_t stream) {
    const float* assign  = (const float*)d_in[0];
    const float* cat     = (const float*)d_in[1];
    const float* alabels = (const float*)d_in[2];
    const float* clabels = (const float*)d_in[3];
    float* out = (float*)d_out;

    const int B = in_sizes[0] / 576;  // 8192
    float* bsums = (float*)d_ws;

    const int nblocks = B / 4;        // 4 batches per 256-thread block
    hipLaunchKernelGGL(hsl_partial, dim3(nblocks), dim3(256), 0, stream,
                       assign, cat, alabels, clabels, bsums);
    hipLaunchKernelGGL(hsl_reduce, dim3(1), dim3(256), 0, stream,
                       bsums, out, B /* = 4*nblocks */, B);
}

// Round 10
// 13.818 us; speedup vs baseline: 1.1392x; 1.1392x over previous
//
#include <hip/hip_runtime.h>
#include <math.h>

// HybridSymmetricLoss: B=8192, P=4, M=12, 24 perms.
// pairS[p][q] = sum_{i,j} (y[p] ? log a[q] : log1p(-a[q]))  (negated BCE)
// best perm = argmax_sigma sum_p pairS[p][sigma(p)]; category BCE via sigma.
// kernel1: 1 batch per 64-lane wave, 4 waves/block, 2048 blocks (r8 main
//   loop). Tail rebuilt for minimal DS-ops (r9 measured ~0.13us per tail
//   DS-op): permlane32/16_swap + DPP quad_perm replace ds_permute/swizzle
//   where possible (31 -> 10 DS ops/wave); argmax via ballot+ctz (first-
//   index tie-break == numpy argmin); category BCE precomputed on 16 lanes
//   at kernel top, gathered with wave-uniform readlane (no DS).
// kernel2: barrier-minimal single-block reduce (r8 exact).

#define LOG2_CLIP (-144.26950408889634f)   // -100 / ln(2)
#define LN2F      (0.6931471805599453f)

typedef int v2i __attribute__((ext_vector_type(2)));

// lane<32: a[lane]+a[lane^32] ; lane>=32: b[lane]+b[lane^32]
__device__ __forceinline__ float pl32_add(float a, float b) {
    v2i r = __builtin_amdgcn_permlane32_swap(__float_as_int(a),
                                             __float_as_int(b), false, false);
    return __int_as_float(r[0]) + __int_as_float(r[1]);
}
// (lane&16)==0: a[lane]+a[lane^16] ; else: b[lane]+b[lane^16]
__device__ __forceinline__ float pl16_add(float a, float b) {
    v2i r = __builtin_amdgcn_permlane16_swap(__float_as_int(a),
                                             __float_as_int(b), false, false);
    return __int_as_float(r[0]) + __int_as_float(r[1]);
}
// DPP quad_perm xor-1 / xor-2 (pure VALU, no LDS pipe)
__device__ __forceinline__ float dpp_x1(float x) {
    return __int_as_float(__builtin_amdgcn_update_dpp(
        0, __float_as_int(x), 0xB1, 0xF, 0xF, false));
}
__device__ __forceinline__ float dpp_x2(float x) {
    return __int_as_float(__builtin_amdgcn_update_dpp(
        0, __float_as_int(x), 0x4E, 0xF, 0xF, false));
}

// perm table, lexicographic. byte p = 16*p + 4*sigma(p) = x-gather lane;
// byte>>2 = 4*p + sigma(p) = catv lane.
#define PK(a,b,c,d) ((unsigned)((4u*(a)) | ((16u+4u*(b))<<8) | \
                                ((32u+4u*(c))<<16) | ((48u+4u*(d))<<24)))
__device__ const unsigned PERM_PK[32] = {
    PK(0,1,2,3), PK(0,1,3,2), PK(0,2,1,3), PK(0,2,3,1), PK(0,3,1,2), PK(0,3,2,1),
    PK(1,0,2,3), PK(1,0,3,2), PK(1,2,0,3), PK(1,2,3,0), PK(1,3,0,2), PK(1,3,2,0),
    PK(2,0,1,3), PK(2,0,3,1), PK(2,1,0,3), PK(2,1,3,0), PK(2,3,0,1), PK(2,3,1,0),
    PK(3,0,1,2), PK(3,0,2,1), PK(3,1,0,2), PK(3,1,2,0), PK(3,2,0,1), PK(3,2,1,0),
    PK(0,1,2,3), PK(0,1,2,3), PK(0,1,2,3), PK(0,1,2,3),
    PK(0,1,2,3), PK(0,1,2,3), PK(0,1,2,3), PK(0,1,2,3)
};

__global__ __launch_bounds__(256) void hsl_partial(
    const float* __restrict__ assign,    // [B,4,12,12]
    const float* __restrict__ cat,       // [B,4]
    const float* __restrict__ alabels,   // [B,4,12,12]
    const float* __restrict__ clabels,   // [B,4]
    float* __restrict__ bsums)           // [nblocks] per-block partial
{
    __shared__ float lred[4];

    const int tid  = (int)threadIdx.x;
    const int wib  = tid >> 6;               // wave in block, 0..3
    const int lane = tid & 63;
    const int b    = (int)blockIdx.x * 4 + wib;

    const float* __restrict__ A = assign  + (size_t)b * 576;
    const float* __restrict__ Y = alabels + (size_t)b * 576;

    // issued early, consumed in the tail
    const unsigned pk = PERM_PK[lane & 31];

    // category BCE table, computed wave-wide concurrently with the main
    // loop: lane (4p+q) [mod 16] holds BCE_log2(cat[q] vs clabels[p]).
    // Both loads hit one 16B line per array; label is exactly 0/1 so the
    // select-argument form is exact.
    float catv;
    {
        const int gq = lane & 3;
        const int gp = (lane >> 2) & 3;
        const float cq  = cat[(size_t)b * 4 + gq];
        const float cyp = clabels[(size_t)b * 4 + gp];
        const float arg = (cyp != 0.0f) ? cq : 1.0f - cq;
        catv = fmaxf(__log2f(arg), LOG2_CLIP);
    }

    // s[4p+q] += y[p]*(la[q]-lb[q]);  T[q] += lb[q]   (log2 domain)
    float s[16], T[4];
#pragma unroll
    for (int i = 0; i < 16; ++i) s[i] = 0.0f;
#pragma unroll
    for (int i = 0; i < 4; ++i) T[i] = 0.0f;

#pragma unroll
    for (int it = 0; it < 3; ++it) {
        if (it < 2 || lane < 16) {           // e = lane + 64*it < 144
            const int e = lane + it * 64;
            float d[4], y[4];
#pragma unroll
            for (int q = 0; q < 4; ++q) {
                const float a  = A[q * 144 + e];
                const float la = fmaxf(__log2f(a),        LOG2_CLIP);
                const float lb = fmaxf(__log2f(1.0f - a), LOG2_CLIP);
                d[q] = la - lb;
                T[q] += lb;
            }
#pragma unroll
            for (int p = 0; p < 4; ++p) y[p] = Y[p * 144 + e];
#pragma unroll
            for (int p = 0; p < 4; ++p)
#pragma unroll
                for (int q = 0; q < 4; ++q)
                    s[p * 4 + q] = fmaf(y[p], d[q], s[p * 4 + q]);
        }
    }
#pragma unroll
    for (int i = 0; i < 16; ++i) s[i] += T[i & 3];

    // ---- reduce-scatter: stage32/16 via permlane swaps (VALU), stage 8/4
    // via ds_swizzle keep/send, stages 2/1 via DPP. Same math as r8. ----
    float t[8];
#pragma unroll
    for (int i = 0; i < 8; ++i) t[i] = pl32_add(s[i], s[i + 8]);
    float u[4];
#pragma unroll
    for (int i = 0; i < 4; ++i) u[i] = pl16_add(t[i], t[i + 4]);

    const bool h8 = (lane & 8) != 0;
    const bool h4 = (lane & 4) != 0;
    float w[2];
#pragma unroll
    for (int i = 0; i < 2; ++i) {
        const float keep = h8 ? u[i + 2] : u[i];
        const float send = h8 ? u[i]     : u[i + 2];
        w[i] = keep + __shfl_xor(send, 8, 64);
    }
    float x;
    {
        const float keep = h4 ? w[1] : w[0];
        const float send = h4 ? w[0] : w[1];
        x = keep + __shfl_xor(send, 4, 64);
    }
    x += dpp_x2(x);
    x += dpp_x1(x);
    // lane l: x == total s[l >> 2]

    // ---- perm-parallel scoring: lane j < 24 evaluates perm j ----
    const int a0 = (int)( pk        & 0xFFu);
    const int a1 = (int)((pk >> 8)  & 0xFFu);
    const int a2 = (int)((pk >> 16) & 0xFFu);
    const int a3 = (int)( pk >> 24        );
    const float v0 = __shfl(x, a0, 64);
    const float v1 = __shfl(x, a1, 64);
    const float v2 = __shfl(x, a2, 64);
    const float v3 = __shfl(x, a3, 64);
    float score = (v0 + v1) + (v2 + v3);
    if (lane >= 24) score = -__builtin_huge_valf();

    // max over the 32-lane group: 3 swizzle + 2 DPP, score only
    float smax = score;
    smax = fmaxf(smax, __shfl_xor(smax, 16, 64));
    smax = fmaxf(smax, __shfl_xor(smax, 8, 64));
    smax = fmaxf(smax, __shfl_xor(smax, 4, 64));
    smax = fmaxf(smax, dpp_x2(smax));
    smax = fmaxf(smax, dpp_x1(smax));

    // winner lane = lowest lane holding the max (== numpy argmin first-index
    // tie-break; lexicographic perm order == lane order). Lanes >= 32 may
    // set high ballot bits (-inf == -inf) -- harmless below bit 24's winner.
    const unsigned long long bal = __ballot(score == smax);
    const int win = (int)__builtin_ctzll(bal);
    const unsigned pkw = (unsigned)__builtin_amdgcn_readlane((int)pk, win);

    // category sum for the winning perm: 4 wave-uniform readlanes on catv
    const int c0 = (int)((pkw >> 2)  & 0x0Fu);
    const int c1 = (int)((pkw >> 10) & 0x0Fu);
    const int c2 = (int)((pkw >> 18) & 0x0Fu);
    const int c3 = (int)((pkw >> 26) & 0x0Fu);
    const float g0 = __int_as_float(__builtin_amdgcn_readlane(__float_as_int(catv), c0));
    const float g1 = __int_as_float(__builtin_amdgcn_readlane(__float_as_int(catv), c1));
    const float g2 = __int_as_float(__builtin_amdgcn_readlane(__float_as_int(catv), c2));
    const float g3 = __int_as_float(__builtin_amdgcn_readlane(__float_as_int(catv), c3));
    const float csum = (g0 + g1) + (g2 + g3);

    if (lane == 0) {
        // per-batch contribution (>= 0): -ln2 * (smax/576 + csum/8)
        lred[wib] = -LN2F * (smax * (1.0f / 576.0f) + 0.125f * csum);
    }
    __syncthreads();

    if (tid == 0) {
        bsums[blockIdx.x] = (lred[0] + lred[1]) + (lred[2] + lred[3]);
    }
}

__global__ __launch_bounds__(256) void hsl_reduce(
    const float* __restrict__ bsums,     // [n] per-block partials
    float* __restrict__ out,
    int n, int B)
{
    __shared__ double sw[4];
    const int tid  = (int)threadIdx.x;
    const int wid  = tid >> 6;
    const int lane = tid & 63;

    const float4* __restrict__ v4 = (const float4*)bsums;
    const int n4 = n >> 2;
    double d = 0.0;
    for (int i = tid; i < n4; i += 256) {
        const float4 v = v4[i];
        d += (double)((v.x + v.y) + (v.z + v.w));
    }

#pragma unroll
    for (int m = 32; m >= 1; m >>= 1)
        d += __shfl_xor(d, m, 64);

    if (lane == 0) sw[wid] = d;
    __syncthreads();

    if (tid == 0) {
        const double t = (sw[0] + sw[1]) + (sw[2] + sw[3]);
        out[0] = (float)(t / (double)B);
    }
}

extern "C" void kernel_launch(void* const* d_in, const int* in_sizes, int n_in,
                              void* d_out, int out_size, void* d_ws, size_t ws_size,
                              hipStream_t stream) {
    const float* assign  = (const float*)d_in[0];
    const float* cat     = (const float*)d_in[1];
    const float* alabels = (const float*)d_in[2];
    const float* clabels = (const float*)d_in[3];
    float* out = (float*)d_out;

    const int B = in_sizes[0] / 576;  // 8192
    float* bsums = (float*)d_ws;

    const int nblocks = B / 4;        // 4 batches per 256-thread block
    hipLaunchKernelGGL(hsl_partial, dim3(nblocks), dim3(256), 0, stream,
                       assign, cat, alabels, clabels, bsums);
    hipLaunchKernelGGL(hsl_reduce, dim3(1), dim3(256), 0, stream,
                       bsums, out, nblocks, B);
}